// Round 15
// baseline (62.668 us; speedup 1.0000x reference)
//
#include <hip/hip_runtime.h>
#include <stdint.h>

#define T_TOK 8192
#define DIMK 1024
#define NEXP 8
#define BM 128
#define BN 128
#define BK 64
#define NTK (DIMK / BK)               /* 16 K-steps */
#define MAXROWS (T_TOK + NEXP * BM)   /* 9216 gathered rows incl. padding */
#define MAXTILES (T_TOK / BM + NEXP)  /* 72 row tiles worst case */
#define NT (DIMK / BN)                /* 8 n tiles */
#define NWG (MAXTILES * NT)           /* 576 blocks, 576 % 8 == 0 */

typedef __attribute__((ext_vector_type(4))) float f32x4;
typedef __attribute__((ext_vector_type(8))) short short8;
typedef __attribute__((ext_vector_type(8))) unsigned short us8;

__device__ __forceinline__ unsigned short f2bf(float f) {
  uint32_t u = __builtin_bit_cast(uint32_t, f);
  u += 0x7FFFu + ((u >> 16) & 1u);   // RTNE
  return (unsigned short)(u >> 16);
}

__device__ __forceinline__ void gload_lds16(const void* g, void* l) {
  __builtin_amdgcn_global_load_lds(
      (const __attribute__((address_space(1))) void*)g,
      (__attribute__((address_space(3))) void*)l, 16, 0, 0);
}

// ---- fused: prep (block 0) || W fp32->bf16 || X fp32->bf16 -----------------
__global__ void k_prep_conv(const int* __restrict__ idx, const float* __restrict__ W,
                            const float* __restrict__ X, int* __restrict__ hdr,
                            int* __restrict__ row2tok, unsigned short* __restrict__ Wb,
                            unsigned short* __restrict__ Xb) {
  const int tid = threadIdx.x;
  const int b = blockIdx.x;
  if (b == 0) {
    __shared__ int h[NEXP];
    __shared__ int cur[NEXP];
    __shared__ int segs[NEXP + 1];
    if (tid < NEXP) h[tid] = 0;
    __syncthreads();
    for (int i = tid; i < T_TOK; i += 256) atomicAdd(&h[idx[i]], 1);
    __syncthreads();
    if (tid == 0) {
      int off = 0;
      for (int e = 0; e < NEXP; e++) {
        segs[e] = off; cur[e] = off;
        hdr[e] = h[e]; hdr[8 + e] = off;
        off += ((h[e] + BM - 1) >> 7) << 7;   // pad to 128-row multiples
      }
      segs[NEXP] = off;
    }
    __syncthreads();
    for (int e = 0; e < NEXP; e++)
      for (int p = segs[e] + h[e] + tid; p < segs[e + 1]; p += 256) row2tok[p] = -1;
    for (int p = segs[NEXP] + tid; p < MAXROWS; p += 256) row2tok[p] = -1;
    for (int i = tid; i < T_TOK; i += 256) {
      int e = idx[i];
      int pos = atomicAdd(&cur[e], 1);
      row2tok[pos] = i;
    }
    return;
  }
  const float* src;
  unsigned short* dst;
  if (b <= 4096) {                    // W: 4096 blocks x 2048 elems
    size_t base = (size_t)(b - 1) * 2048 + tid * 8;
    src = W + base; dst = Wb + base;
  } else {                            // X: 4096 blocks x 2048 elems, token order
    size_t base = (size_t)(b - 4097) * 2048 + tid * 8;
    src = X + base; dst = Xb + base;
  }
  f32x4 v0 = *(const f32x4*)src;
  f32x4 v1 = *(const f32x4*)(src + 4);
  us8 o;
  o[0] = f2bf(v0[0]); o[1] = f2bf(v0[1]); o[2] = f2bf(v0[2]); o[3] = f2bf(v0[3]);
  o[4] = f2bf(v1[0]); o[5] = f2bf(v1[1]); o[6] = f2bf(v1[2]); o[7] = f2bf(v1[3]);
  *(us8*)dst = o;
}

// ---- grouped GEMM with fused A-gather: C[row] = Xb[row2tok[row]] . Wb[e]^T --
// R14 geometry (128x128 tile, 8-wave block, expert-affine XCD map) +
// latency-covered staging: A double-buffered in LDS (gload_lds into buf^1
// issued BEFORE compute on buf), B via register transit (global_load->regs
// issued with the A stage, ds_write after the drain barrier). LDS 48 KB ->
// 3 blocks/CU capacity >= grid 2.25/CU -> ONE dispatch round (the variable
// that killed R4/R6). Load latency is covered by the compute phase; the
// __syncthreads vmcnt(0) drain finds loads already arrived.
__global__ __launch_bounds__(512, 4) void k_gemm(
    const unsigned short* __restrict__ Xb, const unsigned short* __restrict__ Wb,
    const int* __restrict__ hdr, const int* __restrict__ row2tok,
    float* __restrict__ out) {
  __shared__ unsigned short A_lds[2][BM * BK];  // 2 x 16 KB
  __shared__ unsigned short B_lds[BN * BK];     // 16 KB

  // per-expert tile counts
  int T[NEXP];
#pragma unroll
  for (int i = 0; i < NEXP; i++) T[i] = (hdr[i] + BM - 1) >> 7;

  // expert-affine XCD mapping (XCD x -> expert x); overflow via leftover slots
  const int orig = blockIdx.x;
  const int xcd = orig & 7;
  const int slot = orig >> 3;         // 0..71
  int e = -1, tl = 0, nq = 0;
  {
    int P = T[xcd] < 9 ? T[xcd] : 9;
    if (slot < 8 * P) {
      e = xcd; tl = slot % P; nq = slot / P;
    } else {
      int r = slot - 8 * P;
      for (int i = 0; i < xcd; i++) r += 72 - 8 * (T[i] < 9 ? T[i] : 9);
      for (int i = 0; i < NEXP && e < 0; i++) {
        int ot = T[i] - 9;
        if (ot > 0) {
          if (r < 8 * ot) { e = i; tl = 9 + r % ot; nq = r / ot; }
          else r -= 8 * ot;
        }
      }
    }
  }
  if (e < 0) return;
  const int n0 = nq * BN;
  const int row0 = hdr[8 + e] + tl * BM;

  const int tid = threadIdx.x;
  const int lane = tid & 63;
  const int wid = tid >> 6;                 // 0..7
  const int wr = wid >> 2, wc = wid & 3;    // wave grid 2x4, wave tile 64x32

  // staging: lane covers 16B at LDS linear (chunk*1024 + lane*16).
  // LDS row = chunk*8 + (lane>>3); read side XORs col by (row&7)<<4, so the
  // *source* column carries the same XOR (both-sides-or-neither).
  const int st_r = lane >> 3;
  const int st_cb = ((lane & 7) ^ st_r) << 4;

  // A: resolve this lane's 2 row tokens once (pad rows clamp to 0)
  const char* a_lane_base[2];
#pragma unroll
  for (int j = 0; j < 2; j++) {
    int r = (wid * 2 + j) * 8 + st_r;
    int tok = row2tok[row0 + r];
    if (tok < 0) tok = 0;
    a_lane_base[j] = (const char*)Xb + (size_t)tok * (DIMK * 2) + st_cb;
  }
  // B: per-lane global srcs + LDS dsts for the 2 chunks this wave stages
  const char* b_base = (const char*)Wb + ((size_t)e * DIMK * DIMK + (size_t)n0 * DIMK) * 2;
  const char* b_src[2];
  char* b_dst[2];
#pragma unroll
  for (int j = 0; j < 2; j++) {
    int c = wid * 2 + j;
    int r = c * 8 + st_r;
    b_src[j] = b_base + (size_t)r * (DIMK * 2) + st_cb;
    b_dst[j] = (char*)B_lds + c * 1024 + lane * 16;
  }

  f32x4 acc[4][2];
  const f32x4 fzero = {0.f, 0.f, 0.f, 0.f};
#pragma unroll
  for (int m = 0; m < 4; m++)
#pragma unroll
    for (int n = 0; n < 2; n++) acc[m][n] = fzero;

  const int rsel = lane & 15;
  const int swz_r = (lane & 7) << 4;
  const int kgrp = (lane >> 4) << 4;

  int a_row_b[4], b_row_b[2];
#pragma unroll
  for (int m = 0; m < 4; m++) a_row_b[m] = (wr * 64 + m * 16 + rsel) * (BK * 2);
#pragma unroll
  for (int n = 0; n < 2; n++) b_row_b[n] = (wc * 32 + n * 16 + rsel) * (BK * 2);

  // prologue: A(0) -> buf0, B(0) -> regs; drain; write B; publish
  short8 breg[2];
#pragma unroll
  for (int j = 0; j < 2; j++)
    gload_lds16(a_lane_base[j], (char*)A_lds[0] + (wid * 2 + j) * 1024);
#pragma unroll
  for (int j = 0; j < 2; j++) breg[j] = *(const short8*)(b_src[j]);
  __syncthreads();                       // A(0) in LDS, breg arrived
#pragma unroll
  for (int j = 0; j < 2; j++) *(short8*)(b_dst[j]) = breg[j];
  __syncthreads();                       // B_lds visible

  int cur = 0;
#pragma unroll 1
  for (int kt = 0; kt < NTK; kt++) {
    // 1) issue next tile's loads (A async into buf^1, B into regs)
    if (kt + 1 < NTK) {
      const int k0b = (kt + 1) * (BK * 2);
#pragma unroll
      for (int j = 0; j < 2; j++)
        gload_lds16(a_lane_base[j] + k0b, (char*)A_lds[cur ^ 1] + (wid * 2 + j) * 1024);
#pragma unroll
      for (int j = 0; j < 2; j++) breg[j] = *(const short8*)(b_src[j] + k0b);
    }
    // 2) compute on current buffers — covers the loads' latency
#pragma unroll
    for (int ks = 0; ks < 2; ks++) {
      const int kb = ks * 64 + kgrp;
      short8 av[4], bv[2];
#pragma unroll
      for (int m = 0; m < 4; m++)
        av[m] = *(const short8*)((const char*)A_lds[cur] + a_row_b[m] + (kb ^ swz_r));
#pragma unroll
      for (int n = 0; n < 2; n++)
        bv[n] = *(const short8*)((const char*)B_lds + b_row_b[n] + (kb ^ swz_r));
#pragma unroll
      for (int m = 0; m < 4; m++)
#pragma unroll
        for (int n = 0; n < 2; n++)
          acc[m][n] = __builtin_amdgcn_mfma_f32_16x16x32_bf16(av[m], bv[n], acc[m][n], 0, 0, 0);
    }
    // 3) drain: all B_lds reads done block-wide; vmcnt(0) finds loads arrived
    __syncthreads();
    // 4) publish next B tile
    if (kt + 1 < NTK) {
#pragma unroll
      for (int j = 0; j < 2; j++) *(short8*)(b_dst[j]) = breg[j];
    }
    __syncthreads();
    cur ^= 1;
  }

  // epilogue: scatter rows back to tokens; pad rows have row2tok == -1
  const int rg4 = (lane >> 4) * 4;
#pragma unroll
  for (int m = 0; m < 4; m++) {
#pragma unroll
    for (int i = 0; i < 4; i++) {
      int rg = row0 + wr * 64 + m * 16 + rg4 + i;
      int tok = row2tok[rg];
      if (tok >= 0) {
        float* po = out + (size_t)tok * DIMK + n0 + wc * 32 + rsel;
#pragma unroll
        for (int n = 0; n < 2; n++) po[n * 16] = acc[m][n][i];
      }
    }
  }
}

extern "C" void kernel_launch(void* const* d_in, const int* in_sizes, int n_in,
                              void* d_out, int out_size, void* d_ws, size_t ws_size,
                              hipStream_t stream) {
  const float* X = (const float*)d_in[0];
  const float* W = (const float*)d_in[1];
  const int* idx = (const int*)d_in[2];
  float* out = (float*)d_out;
  char* ws = (char*)d_ws;

  int* hdr = (int*)ws;                                     // 64 ints
  int* row2tok = (int*)(ws + 256);                         // 9216 ints
  unsigned short* Wb = (unsigned short*)(ws + 65536);      // 16 MiB bf16 W
  unsigned short* Xb = (unsigned short*)(ws + 65536 + 16777216);  // 16 MiB bf16 X (token order)

  k_prep_conv<<<8193, 256, 0, stream>>>(idx, W, X, hdr, row2tok, Wb, Xb);
  k_gemm<<<NWG, 512, 0, stream>>>(Xb, Wb, hdr, row2tok, out);
}

// Round 16
// 59.978 us; speedup vs baseline: 1.0448x; 1.0448x over previous
//
#include <hip/hip_runtime.h>
#include <stdint.h>

#define T_TOK 8192
#define DIMK 1024
#define NEXP 8
#define BM 128
#define BN 128
#define BK 64
#define NTK (DIMK / BK)               /* 16 K-steps */
#define MAXROWS (T_TOK + NEXP * BM)   /* 9216 gathered rows incl. padding */
#define MAXTILES (T_TOK / BM + NEXP)  /* 72 row tiles worst case */
#define NT (DIMK / BN)                /* 8 n tiles */
#define NWG (MAXTILES * NT)           /* 576 blocks, 576 % 8 == 0 */

typedef __attribute__((ext_vector_type(4))) float f32x4;
typedef __attribute__((ext_vector_type(8))) short short8;
typedef __attribute__((ext_vector_type(8))) unsigned short us8;

__device__ __forceinline__ unsigned short f2bf(float f) {
  uint32_t u = __builtin_bit_cast(uint32_t, f);
  u += 0x7FFFu + ((u >> 16) & 1u);   // RTNE
  return (unsigned short)(u >> 16);
}

__device__ __forceinline__ void gload_lds16(const void* g, void* l) {
  __builtin_amdgcn_global_load_lds(
      (const __attribute__((address_space(1))) void*)g,
      (__attribute__((address_space(3))) void*)l, 16, 0, 0);
}

// ---- fused: per-expert prep (blocks 0-7) || W,X fp32->bf16 (blocks 8+) -----
// Prep parallelized 8x: block e re-derives the full histogram from idx (32KB,
// L2-resident), prefix-sums padded counts for its segment start, marks ONLY
// its pads, assigns ONLY its tokens. Removes the single-block straggler that
// ran past the 16 us conversion stream. Parts are mutually independent.
__global__ void k_prep_conv(const int* __restrict__ idx, const float* __restrict__ W,
                            const float* __restrict__ X, int* __restrict__ hdr,
                            int* __restrict__ row2tok, unsigned short* __restrict__ Wb,
                            unsigned short* __restrict__ Xb) {
  const int tid = threadIdx.x;
  const int b = blockIdx.x;
  if (b < NEXP) {
    const int e = b;
    __shared__ int h[NEXP];
    __shared__ int cur;
    if (tid < NEXP) h[tid] = 0;
    if (tid == 0) cur = 0;
    __syncthreads();
    for (int i = tid; i < T_TOK; i += 256) atomicAdd(&h[idx[i]], 1);
    __syncthreads();
    int seg = 0;
    for (int i = 0; i < e; i++) seg += ((h[i] + BM - 1) >> 7) << 7;
    const int cnt = h[e];
    const int padded = ((cnt + BM - 1) >> 7) << 7;
    if (tid == 0) { hdr[e] = cnt; hdr[8 + e] = seg; }
    // pad markers for this segment's tail only (rows past seg+padded are
    // never read by the GEMM: tiles stop at padded/BM)
    for (int p = seg + cnt + tid; p < seg + padded; p += 256) row2tok[p] = -1;
    // assign this expert's tokens (any intra-segment order is valid: every
    // row computes the identical K-loop, so output values are order-invariant)
    for (int i = tid; i < T_TOK; i += 256) {
      if (idx[i] == e) {
        int pos = atomicAdd(&cur, 1);
        row2tok[seg + pos] = i;
      }
    }
    return;
  }
  const int cb = b - NEXP;
  const float* src;
  unsigned short* dst;
  if (cb < 4096) {                    // W: 4096 blocks x 2048 elems
    size_t base = (size_t)cb * 2048 + tid * 8;
    src = W + base; dst = Wb + base;
  } else {                            // X: 4096 blocks x 2048 elems, token order
    size_t base = (size_t)(cb - 4096) * 2048 + tid * 8;
    src = X + base; dst = Xb + base;
  }
  f32x4 v0 = *(const f32x4*)src;
  f32x4 v1 = *(const f32x4*)(src + 4);
  us8 o;
  o[0] = f2bf(v0[0]); o[1] = f2bf(v0[1]); o[2] = f2bf(v0[2]); o[3] = f2bf(v0[3]);
  o[4] = f2bf(v1[0]); o[5] = f2bf(v1[1]); o[6] = f2bf(v1[2]); o[7] = f2bf(v1[3]);
  *(us8*)dst = o;
}

// ---- grouped GEMM with fused A-gather: C[row] = Xb[row2tok[row]] . Wb[e]^T --
// R14 exactly (proven best): 128x128 tile, 512-thread 8-wave block, single-
// buffer 2-barrier K-loop, expert-affine XCD mapping (XCD x -> expert x, per-
// XCD working set ~4MB -> L2-local), T2 swizzle, fused per-lane A-gather.
__global__ __launch_bounds__(512, 6) void k_gemm(
    const unsigned short* __restrict__ Xb, const unsigned short* __restrict__ Wb,
    const int* __restrict__ hdr, const int* __restrict__ row2tok,
    float* __restrict__ out) {
  __shared__ unsigned short A_lds[BM * BK];  // 16 KB
  __shared__ unsigned short B_lds[BN * BK];  // 16 KB

  // per-expert tile counts
  int T[NEXP];
#pragma unroll
  for (int i = 0; i < NEXP; i++) T[i] = (hdr[i] + BM - 1) >> 7;

  const int orig = blockIdx.x;
  const int xcd = orig & 7;           // HW: consecutive blocks round-robin XCDs
  const int slot = orig >> 3;         // 0..71 within this XCD
  int e = -1, tl = 0, nq = 0;
  {
    int P = T[xcd] < 9 ? T[xcd] : 9;  // primary tiles on home XCD
    if (slot < 8 * P) {
      e = xcd; tl = slot % P; nq = slot / P;
    } else {
      // leftover slot: global rank over all XCDs' spare slots
      int r = slot - 8 * P;
      for (int i = 0; i < xcd; i++) r += 72 - 8 * (T[i] < 9 ? T[i] : 9);
      // map rank -> overflow units (experts with T>9), in expert order
      for (int i = 0; i < NEXP && e < 0; i++) {
        int ot = T[i] - 9;
        if (ot > 0) {
          if (r < 8 * ot) { e = i; tl = 9 + r % ot; nq = r / ot; }
          else r -= 8 * ot;
        }
      }
    }
  }
  if (e < 0) return;
  const int n0 = nq * BN;             // output column base
  const int row0 = hdr[8 + e] + tl * BM;

  const int tid = threadIdx.x;
  const int lane = tid & 63;
  const int wid = tid >> 6;                 // 0..7
  const int wr = wid >> 2, wc = wid & 3;    // wave grid 2x4, wave tile 64x32

  // staging: lane covers 16B at LDS linear (chunk*1024 + lane*16).
  // LDS row = chunk*8 + (lane>>3); read side XORs col by (row&7)<<4, so the
  // *source* column carries the same XOR (both-sides-or-neither).
  const int st_r = lane >> 3;
  const int st_cb = ((lane & 7) ^ st_r) << 4;

  // resolve this lane's 2 A-row tokens ONCE (rows fixed across K-steps).
  // pad rows (tok=-1) clamp to row 0: garbage values, outputs never stored.
  const char* a_lane_base[2];
#pragma unroll
  for (int j = 0; j < 2; j++) {
    int r = (wid * 2 + j) * 8 + st_r;
    int tok = row2tok[row0 + r];
    if (tok < 0) tok = 0;
    a_lane_base[j] = (const char*)Xb + (size_t)tok * (DIMK * 2) + st_cb;
  }
  const char* b_base = (const char*)Wb + ((size_t)e * DIMK * DIMK + (size_t)n0 * DIMK) * 2;

  f32x4 acc[4][2];
  const f32x4 fzero = {0.f, 0.f, 0.f, 0.f};
#pragma unroll
  for (int m = 0; m < 4; m++)
#pragma unroll
    for (int n = 0; n < 2; n++) acc[m][n] = fzero;

  const int rsel = lane & 15;
  const int swz_r = (lane & 7) << 4;
  const int kgrp = (lane >> 4) << 4;

  int a_row_b[4], b_row_b[2];
#pragma unroll
  for (int m = 0; m < 4; m++) a_row_b[m] = (wr * 64 + m * 16 + rsel) * (BK * 2);
#pragma unroll
  for (int n = 0; n < 2; n++) b_row_b[n] = (wc * 32 + n * 16 + rsel) * (BK * 2);

  for (int kt = 0; kt < NTK; kt++) {
    const int k0b = kt * (BK * 2);
    // stage A (16 chunks) + B (16 chunks); 4 gload_lds per wave
#pragma unroll
    for (int j = 0; j < 2; j++) {
      int c = wid * 2 + j;
      int r = c * 8 + st_r;
      gload_lds16(a_lane_base[j] + k0b, (char*)A_lds + c * 1024);
      gload_lds16(b_base + (size_t)r * (DIMK * 2) + k0b + st_cb, (char*)B_lds + c * 1024);
    }
    __syncthreads();
#pragma unroll
    for (int ks = 0; ks < 2; ks++) {
      const int kb = ks * 64 + kgrp;
      short8 av[4], bv[2];
#pragma unroll
      for (int m = 0; m < 4; m++)
        av[m] = *(const short8*)((const char*)A_lds + a_row_b[m] + (kb ^ swz_r));
#pragma unroll
      for (int n = 0; n < 2; n++)
        bv[n] = *(const short8*)((const char*)B_lds + b_row_b[n] + (kb ^ swz_r));
#pragma unroll
      for (int m = 0; m < 4; m++)
#pragma unroll
        for (int n = 0; n < 2; n++)
          acc[m][n] = __builtin_amdgcn_mfma_f32_16x16x32_bf16(av[m], bv[n], acc[m][n], 0, 0, 0);
    }
    __syncthreads();
  }

  // epilogue: scatter rows back to tokens; pad rows have row2tok == -1
  const int rg4 = (lane >> 4) * 4;
#pragma unroll
  for (int m = 0; m < 4; m++) {
#pragma unroll
    for (int i = 0; i < 4; i++) {
      int rg = row0 + wr * 64 + m * 16 + rg4 + i;
      int tok = row2tok[rg];
      if (tok >= 0) {
        float* po = out + (size_t)tok * DIMK + n0 + wc * 32 + rsel;
#pragma unroll
        for (int n = 0; n < 2; n++) po[n * 16] = acc[m][n][i];
      }
    }
  }
}

extern "C" void kernel_launch(void* const* d_in, const int* in_sizes, int n_in,
                              void* d_out, int out_size, void* d_ws, size_t ws_size,
                              hipStream_t stream) {
  const float* X = (const float*)d_in[0];
  const float* W = (const float*)d_in[1];
  const int* idx = (const int*)d_in[2];
  float* out = (float*)d_out;
  char* ws = (char*)d_ws;

  int* hdr = (int*)ws;                                     // 64 ints
  int* row2tok = (int*)(ws + 256);                         // 9216 ints
  unsigned short* Wb = (unsigned short*)(ws + 65536);      // 16 MiB bf16 W
  unsigned short* Xb = (unsigned short*)(ws + 65536 + 16777216);  // 16 MiB bf16 X (token order)

  k_prep_conv<<<NEXP + 8192, 256, 0, stream>>>(idx, W, X, hdr, row2tok, Wb, Xb);
  k_gemm<<<NWG, 512, 0, stream>>>(Xb, Wb, hdr, row2tok, out);
}

// Round 17
// 52.023 us; speedup vs baseline: 1.2046x; 1.1529x over previous
//
#include <hip/hip_runtime.h>
#include <stdint.h>

#define T_TOK 8192
#define DIMK 1024
#define NEXP 8
#define BM 128
#define BN 128
#define BK 64
#define NTK (DIMK / BK)               /* 16 K-steps */
#define MAXROWS (T_TOK + NEXP * BM)   /* 9216 gathered rows incl. padding */
#define MAXTILES (T_TOK / BM + NEXP)  /* 72 row tiles worst case */
#define NT (DIMK / BN)                /* 8 n tiles */
#define NWG (MAXTILES * NT)           /* 576 blocks, 576 % 8 == 0 */

typedef __attribute__((ext_vector_type(4))) float f32x4;
typedef __attribute__((ext_vector_type(4))) int i32x4;
typedef __attribute__((ext_vector_type(8))) short short8;
typedef __attribute__((ext_vector_type(8))) unsigned short us8;

__device__ __forceinline__ unsigned short f2bf(float f) {
  uint32_t u = __builtin_bit_cast(uint32_t, f);
  u += 0x7FFFu + ((u >> 16) & 1u);   // RTNE
  return (unsigned short)(u >> 16);
}

__device__ __forceinline__ void gload_lds16(const void* g, void* l) {
  __builtin_amdgcn_global_load_lds(
      (const __attribute__((address_space(1))) void*)g,
      (__attribute__((address_space(3))) void*)l, 16, 0, 0);
}

// ---- fused: per-expert prep (blocks 0-7) || W,X fp32->bf16 (blocks 8+) -----
// Prep scans vectorized 4x (int4 idx loads): 8 latency-bound iterations per
// scan instead of 32, so the 8 prep blocks finish well under the ~15us
// conversion stream (R16 cut phase count; this cuts scan depth).
__global__ void k_prep_conv(const int* __restrict__ idx, const float* __restrict__ W,
                            const float* __restrict__ X, int* __restrict__ hdr,
                            int* __restrict__ row2tok, unsigned short* __restrict__ Wb,
                            unsigned short* __restrict__ Xb) {
  const int tid = threadIdx.x;
  const int b = blockIdx.x;
  if (b < NEXP) {
    const int e = b;
    __shared__ int h[NEXP];
    __shared__ int cur;
    if (tid < NEXP) h[tid] = 0;
    if (tid == 0) cur = 0;
    __syncthreads();
    // histogram: int4 loads, 8 iterations
    for (int i = tid * 4; i < T_TOK; i += 1024) {
      i32x4 v = *(const i32x4*)(idx + i);
      atomicAdd(&h[v[0]], 1); atomicAdd(&h[v[1]], 1);
      atomicAdd(&h[v[2]], 1); atomicAdd(&h[v[3]], 1);
    }
    __syncthreads();
    int seg = 0;
    for (int i = 0; i < e; i++) seg += ((h[i] + BM - 1) >> 7) << 7;
    const int cnt = h[e];
    const int padded = ((cnt + BM - 1) >> 7) << 7;
    if (tid == 0) { hdr[e] = cnt; hdr[8 + e] = seg; }
    // pad markers for this segment's tail only (rows past seg+padded are
    // never read by the GEMM: tiles stop at padded/BM)
    for (int p = seg + cnt + tid; p < seg + padded; p += 256) row2tok[p] = -1;
    // assign this expert's tokens (intra-segment order arbitrary: every row
    // computes the identical K-loop, so output values are order-invariant)
    for (int i = tid * 4; i < T_TOK; i += 1024) {
      i32x4 v = *(const i32x4*)(idx + i);
#pragma unroll
      for (int j = 0; j < 4; j++) {
        if (v[j] == e) {
          int pos = atomicAdd(&cur, 1);
          row2tok[seg + pos] = i + j;
        }
      }
    }
    return;
  }
  const int cb = b - NEXP;
  const float* src;
  unsigned short* dst;
  if (cb < 4096) {                    // W: 4096 blocks x 2048 elems
    size_t base = (size_t)cb * 2048 + tid * 8;
    src = W + base; dst = Wb + base;
  } else {                            // X: 4096 blocks x 2048 elems, token order
    size_t base = (size_t)(cb - 4096) * 2048 + tid * 8;
    src = X + base; dst = Xb + base;
  }
  f32x4 v0 = *(const f32x4*)src;
  f32x4 v1 = *(const f32x4*)(src + 4);
  us8 o;
  o[0] = f2bf(v0[0]); o[1] = f2bf(v0[1]); o[2] = f2bf(v0[2]); o[3] = f2bf(v0[3]);
  o[4] = f2bf(v1[0]); o[5] = f2bf(v1[1]); o[6] = f2bf(v1[2]); o[7] = f2bf(v1[3]);
  *(us8*)dst = o;
}

// ---- grouped GEMM with fused A-gather: C[row] = Xb[row2tok[row]] . Wb[e]^T --
// R14 exactly (proven best over 8 tile configs + 7 pipeline variants):
// 128x128 tile, 512-thread 8-wave block, single-buffer 2-barrier K-loop,
// expert-affine XCD mapping, T2 swizzle, fused per-lane A-gather.
__global__ __launch_bounds__(512, 6) void k_gemm(
    const unsigned short* __restrict__ Xb, const unsigned short* __restrict__ Wb,
    const int* __restrict__ hdr, const int* __restrict__ row2tok,
    float* __restrict__ out) {
  __shared__ unsigned short A_lds[BM * BK];  // 16 KB
  __shared__ unsigned short B_lds[BN * BK];  // 16 KB

  // per-expert tile counts
  int T[NEXP];
#pragma unroll
  for (int i = 0; i < NEXP; i++) T[i] = (hdr[i] + BM - 1) >> 7;

  const int orig = blockIdx.x;
  const int xcd = orig & 7;           // HW: consecutive blocks round-robin XCDs
  const int slot = orig >> 3;         // 0..71 within this XCD
  int e = -1, tl = 0, nq = 0;
  {
    int P = T[xcd] < 9 ? T[xcd] : 9;  // primary tiles on home XCD
    if (slot < 8 * P) {
      e = xcd; tl = slot % P; nq = slot / P;
    } else {
      // leftover slot: global rank over all XCDs' spare slots
      int r = slot - 8 * P;
      for (int i = 0; i < xcd; i++) r += 72 - 8 * (T[i] < 9 ? T[i] : 9);
      // map rank -> overflow units (experts with T>9), in expert order
      for (int i = 0; i < NEXP && e < 0; i++) {
        int ot = T[i] - 9;
        if (ot > 0) {
          if (r < 8 * ot) { e = i; tl = 9 + r % ot; nq = r / ot; }
          else r -= 8 * ot;
        }
      }
    }
  }
  if (e < 0) return;
  const int n0 = nq * BN;             // output column base
  const int row0 = hdr[8 + e] + tl * BM;

  const int tid = threadIdx.x;
  const int lane = tid & 63;
  const int wid = tid >> 6;                 // 0..7
  const int wr = wid >> 2, wc = wid & 3;    // wave grid 2x4, wave tile 64x32

  // staging: lane covers 16B at LDS linear (chunk*1024 + lane*16).
  // LDS row = chunk*8 + (lane>>3); read side XORs col by (row&7)<<4, so the
  // *source* column carries the same XOR (both-sides-or-neither).
  const int st_r = lane >> 3;
  const int st_cb = ((lane & 7) ^ st_r) << 4;

  // resolve this lane's 2 A-row tokens ONCE (rows fixed across K-steps).
  // pad rows (tok=-1) clamp to row 0: garbage values, outputs never stored.
  const char* a_lane_base[2];
#pragma unroll
  for (int j = 0; j < 2; j++) {
    int r = (wid * 2 + j) * 8 + st_r;
    int tok = row2tok[row0 + r];
    if (tok < 0) tok = 0;
    a_lane_base[j] = (const char*)Xb + (size_t)tok * (DIMK * 2) + st_cb;
  }
  const char* b_base = (const char*)Wb + ((size_t)e * DIMK * DIMK + (size_t)n0 * DIMK) * 2;

  f32x4 acc[4][2];
  const f32x4 fzero = {0.f, 0.f, 0.f, 0.f};
#pragma unroll
  for (int m = 0; m < 4; m++)
#pragma unroll
    for (int n = 0; n < 2; n++) acc[m][n] = fzero;

  const int rsel = lane & 15;
  const int swz_r = (lane & 7) << 4;
  const int kgrp = (lane >> 4) << 4;

  int a_row_b[4], b_row_b[2];
#pragma unroll
  for (int m = 0; m < 4; m++) a_row_b[m] = (wr * 64 + m * 16 + rsel) * (BK * 2);
#pragma unroll
  for (int n = 0; n < 2; n++) b_row_b[n] = (wc * 32 + n * 16 + rsel) * (BK * 2);

  for (int kt = 0; kt < NTK; kt++) {
    const int k0b = kt * (BK * 2);
    // stage A (16 chunks) + B (16 chunks); 4 gload_lds per wave
#pragma unroll
    for (int j = 0; j < 2; j++) {
      int c = wid * 2 + j;
      int r = c * 8 + st_r;
      gload_lds16(a_lane_base[j] + k0b, (char*)A_lds + c * 1024);
      gload_lds16(b_base + (size_t)r * (DIMK * 2) + k0b + st_cb, (char*)B_lds + c * 1024);
    }
    __syncthreads();
#pragma unroll
    for (int ks = 0; ks < 2; ks++) {
      const int kb = ks * 64 + kgrp;
      short8 av[4], bv[2];
#pragma unroll
      for (int m = 0; m < 4; m++)
        av[m] = *(const short8*)((const char*)A_lds + a_row_b[m] + (kb ^ swz_r));
#pragma unroll
      for (int n = 0; n < 2; n++)
        bv[n] = *(const short8*)((const char*)B_lds + b_row_b[n] + (kb ^ swz_r));
#pragma unroll
      for (int m = 0; m < 4; m++)
#pragma unroll
        for (int n = 0; n < 2; n++)
          acc[m][n] = __builtin_amdgcn_mfma_f32_16x16x32_bf16(av[m], bv[n], acc[m][n], 0, 0, 0);
    }
    __syncthreads();
  }

  // epilogue: scatter rows back to tokens; pad rows have row2tok == -1
  const int rg4 = (lane >> 4) * 4;
#pragma unroll
  for (int m = 0; m < 4; m++) {
#pragma unroll
    for (int i = 0; i < 4; i++) {
      int rg = row0 + wr * 64 + m * 16 + rg4 + i;
      int tok = row2tok[rg];
      if (tok >= 0) {
        float* po = out + (size_t)tok * DIMK + n0 + wc * 32 + rsel;
#pragma unroll
        for (int n = 0; n < 2; n++) po[n * 16] = acc[m][n][i];
      }
    }
  }
}

extern "C" void kernel_launch(void* const* d_in, const int* in_sizes, int n_in,
                              void* d_out, int out_size, void* d_ws, size_t ws_size,
                              hipStream_t stream) {
  const float* X = (const float*)d_in[0];
  const float* W = (const float*)d_in[1];
  const int* idx = (const int*)d_in[2];
  float* out = (float*)d_out;
  char* ws = (char*)d_ws;

  int* hdr = (int*)ws;                                     // 64 ints
  int* row2tok = (int*)(ws + 256);                         // 9216 ints
  unsigned short* Wb = (unsigned short*)(ws + 65536);      // 16 MiB bf16 W
  unsigned short* Xb = (unsigned short*)(ws + 65536 + 16777216);  // 16 MiB bf16 X (token order)

  k_prep_conv<<<NEXP + 8192, 256, 0, stream>>>(idx, W, X, hdr, row2tok, Wb, Xb);
  k_gemm<<<NWG, 512, 0, stream>>>(Xb, Wb, hdr, row2tok, out);
}